// Round 14
// baseline (267.445 us; speedup 1.0000x reference)
//
#include <hip/hip_runtime.h>

// Problem constants (fixed by the reference)
#define N2 2048
#define NNZ 32768
#define LK 22          // FROZEN: absmax 0.0234 of 0.037 threshold (3 of ~4.7 bf16 ulps)
#define NBL 128        // lanczos grid blocks: 128 x 512 thr; 147KB LDS -> 1 block/CU
#define BINCAP 64      // slots per bin (Poisson(16) tail ~1e-15)

typedef __attribute__((ext_vector_type(8))) _Float16 half8;
typedef __attribute__((ext_vector_type(4))) float f32x4;

#define AGENT __HIP_MEMORY_SCOPE_AGENT
#define AS1C(p) ((const __attribute__((address_space(1))) unsigned int*)(p))
#define AS3(p)  ((__attribute__((address_space(3))) unsigned int*)(p))

__device__ __forceinline__ unsigned short f2h(float f) {
  _Float16 h = (_Float16)f;                   // fp16 RNE
  return *(unsigned short*)&h;
}

// ==== R29 pipeline:  M = L A L^T,  L = I + S,  A = WW^T/N + I
//   = (L Wh)(L Wh)^T / N + I   [dense part: gatherG + symmetric GEMM]
//   + S + S^T + S S^T          [sparse part: applied INSIDE lanczos, in LDS]
// R13 ledger-solve: GEMM~48us, gather~35us, global-atomic scatter ~54us
// (0.7M random-cacheline RMWs — modeled FLOPs, paid cachelines). The sparse
// term touches only each lanczos block's OWN 16 staged rows -> apply it there
// via LDS atomicAdd (~4.6K adds + 32KB L2-hot bin reads per block, ~1-2us).

// ---- 1. W (fp32) -> fp16; zero row/col bin counters ----
__global__ __launch_bounds__(256) void convert_kernel(const float* __restrict__ W,
                                                      unsigned short* __restrict__ Hf,
                                                      unsigned* __restrict__ cntR,
                                                      unsigned* __restrict__ cntC) {
  if (blockIdx.x < 8)       cntR[blockIdx.x * 256 + threadIdx.x] = 0;
  else if (blockIdx.x < 16) cntC[(blockIdx.x - 8) * 256 + threadIdx.x] = 0;
  int i4 = blockIdx.x * 256 + threadIdx.x;          // grid 4096 -> 1048576 float4s
  float4 w = ((const float4*)W)[i4];
  ushort4 h;
  h.x = f2h(w.x); h.y = f2h(w.y); h.z = f2h(w.z); h.w = f2h(w.w);
  ((ushort4*)Hf)[i4] = h;
}

// ---- 2. fill row bins (G-gather, SS^T) and column bins (S^T, SS^T) ----
__global__ __launch_bounds__(256) void fill_kernel(const float* __restrict__ pred,
                                                   const float* __restrict__ scal,
                                                   const int* __restrict__ rows,
                                                   const int* __restrict__ cols,
                                                   unsigned* __restrict__ cntR,
                                                   int* __restrict__ binRc,
                                                   float* __restrict__ binRv,
                                                   unsigned* __restrict__ cntC,
                                                   int* __restrict__ binCr,
                                                   float* __restrict__ binCv) {
  int k = blockIdx.x * 256 + threadIdx.x;
  int r = rows[k], c = cols[k];
  float v = pred[k] * scal[k];
  unsigned pR = atomicAdd(&cntR[r], 1u);
  if (pR < BINCAP) { binRc[r * BINCAP + pR] = c; binRv[r * BINCAP + pR] = v; }
  unsigned pC = atomicAdd(&cntC[c], 1u);
  if (pC < BINCAP) { binCr[c * BINCAP + pC] = r; binCv[c * BINCAP + pC] = v; }
}

// ---- 3. G[r,:] = Hf[r,:] + sum_e v_e * Hf[c_e,:]  (fp16 out, fp32 acc, MLP-8) ----
__global__ __launch_bounds__(256) void gatherG_kernel(const unsigned* __restrict__ cntR,
                                                      const int* __restrict__ binRc,
                                                      const float* __restrict__ binRv,
                                                      const unsigned short* __restrict__ Hf,
                                                      unsigned short* __restrict__ Gh) {
  const int r = blockIdx.x, tid = threadIdx.x;
  __shared__ int scol_[BINCAP];
  __shared__ float sval_[BINCAP];
  const unsigned ne = min(cntR[r], (unsigned)BINCAP);
  if (tid < ne) {
    scol_[tid] = binRc[r * BINCAP + tid];
    sval_[tid] = binRv[r * BINCAP + tid];
  }
  __syncthreads();
  // init from own row (the I in L = I + S)
  uint4 own = *(const uint4*)(Hf + (size_t)r * 2048 + tid * 8);
  half8 ho = *(half8*)&own;
  float acc[8];
#pragma unroll
  for (int k = 0; k < 8; ++k) acc[k] = (float)ho[k];
  unsigned e = 0;
  for (; e + 8 <= ne; e += 8) {
    uint4 q[8];
#pragma unroll
    for (int u = 0; u < 8; ++u)
      q[u] = *(const uint4*)(Hf + (size_t)scol_[e + u] * 2048 + tid * 8);
#pragma unroll
    for (int u = 0; u < 8; ++u) {
      half8 hv = *(half8*)&q[u];
      const float v = sval_[e + u];
#pragma unroll
      for (int k = 0; k < 8; ++k) acc[k] += v * (float)hv[k];
    }
  }
  for (; e + 4 <= ne; e += 4) {
    uint4 q[4];
#pragma unroll
    for (int u = 0; u < 4; ++u)
      q[u] = *(const uint4*)(Hf + (size_t)scol_[e + u] * 2048 + tid * 8);
#pragma unroll
    for (int u = 0; u < 4; ++u) {
      half8 hv = *(half8*)&q[u];
      const float v = sval_[e + u];
#pragma unroll
      for (int k = 0; k < 8; ++k) acc[k] += v * (float)hv[k];
    }
  }
  for (; e < ne; ++e) {
    uint4 qq = *(const uint4*)(Hf + (size_t)scol_[e] * 2048 + tid * 8);
    half8 hv = *(half8*)&qq;
    const float v = sval_[e];
#pragma unroll
    for (int k = 0; k < 8; ++k) acc[k] += v * (float)hv[k];
  }
  unsigned short o[8];
#pragma unroll
  for (int k = 0; k < 8; ++k) o[k] = f2h(acc[k]);
  *(uint4*)(Gh + (size_t)r * 2048 + tid * 8) = *(uint4*)o;
}

// ---- 4. M = G*G^T/N + I — symmetric-half (R23) + dbuf split-K (R24), fp32 out.
//      64x128 tile, 272 blocks (32 diag-band full + 240 lower w/ fp32 mirror).
__device__ __forceinline__ void stage_tiles2(const unsigned short* __restrict__ X,
                                             unsigned short* Xb, unsigned short* Yb,
                                             int row0, int col0, int kk,
                                             int srowX, int srowY, int scol, int wq) {
  __builtin_amdgcn_global_load_lds(
      AS1C(X + (size_t)(row0 + srowX) * 2048 + kk + scol),
      AS3(Xb + (wq * 16) * 32), 16, 0, 0);
#pragma unroll
  for (int q = 0; q < 2; ++q) {
    __builtin_amdgcn_global_load_lds(
        AS1C(X + (size_t)(col0 + srowY + q * 16) * 2048 + kk + scol),
        AS3(Yb + (wq * 32 + q * 16) * 32), 16, 0, 0);
  }
}

__global__ __launch_bounds__(512) void gemmM_kernel(const unsigned short* __restrict__ Gh,
                                                    float* __restrict__ M) {
  const int tid = threadIdx.x;
  // tile mapping: 32 diag-band + 240 pure-lower (R23)
  int bi, bj;
  bool diag;
  if (blockIdx.x < 32) {
    bi = blockIdx.x; bj = bi >> 1; diag = true;
  } else {
    int idx = blockIdx.x - 32;                // 0..239
    int j = 0;                                 // off(j) = j*(31-j)
    while (j < 14 && idx >= (j + 1) * (30 - j)) ++j;
    bj = j;
    bi = 2 * j + 2 + (idx - j * (31 - j));
    diag = false;
  }

  __shared__ __align__(16) char smem[49152];   // 48KB staging; Cred aliases after
  unsigned short* Xs = (unsigned short*)smem;             // [half][buf][64*32]
  unsigned short* Ys = (unsigned short*)(smem + 16384);   // [half][buf][128*32]
  float* Cred = (float*)smem;                             // [64*132] post-loop

  const int w = tid >> 6, lane = tid & 63;
  const int half = w >> 2, wq = w & 3;      // k-half, role within half
  const int row0 = bi * 64, col0 = bj * 128;
  const int m0 = (wq & 1) * 32, n0 = (wq >> 1) * 64;
  f32x4 acc[2][4];
#pragma unroll
  for (int a = 0; a < 2; ++a)
#pragma unroll
    for (int b = 0; b < 4; ++b) acc[a][b] = (f32x4){0.f, 0.f, 0.f, 0.f};
  const int mrow = lane & 15, kseg = (lane >> 4) * 8;
  const int srowX = wq * 16 + (lane >> 2);
  const int srowY = wq * 32 + (lane >> 2);
  const int scol = (lane & 3) * 8;
  const int kbase = half * 1024;

  stage_tiles2(Gh, Xs + (half * 2 + 0) * 2048, Ys + (half * 2 + 0) * 4096,
               row0, col0, kbase, srowX, srowY, scol, wq);
  for (int t = 0; t < 32; ++t) {
    const int cur = t & 1;
    __syncthreads();
    if (t < 31)
      stage_tiles2(Gh, Xs + (half * 2 + (cur ^ 1)) * 2048,
                   Ys + (half * 2 + (cur ^ 1)) * 4096,
                   row0, col0, kbase + (t + 1) * 32, srowX, srowY, scol, wq);
    const unsigned short* Xb = Xs + (half * 2 + cur) * 2048;
    const unsigned short* Yb = Ys + (half * 2 + cur) * 4096;
    half8 af[2], bf[4];
#pragma unroll
    for (int q = 0; q < 2; ++q)
      af[q] = *(const half8*)(Xb + (m0 + q * 16 + mrow) * 32 + kseg);
#pragma unroll
    for (int q = 0; q < 4; ++q)
      bf[q] = *(const half8*)(Yb + (n0 + q * 16 + mrow) * 32 + kseg);
#pragma unroll
    for (int mt = 0; mt < 2; ++mt)
#pragma unroll
      for (int nt = 0; nt < 4; ++nt)
        acc[mt][nt] = __builtin_amdgcn_mfma_f32_16x16x32_f16(af[mt], bf[nt], acc[mt][nt], 0, 0, 0);
  }
  // combine halves; epilogue applies /N + I; fp32 direct + fp32 mirror.
  // C/D layout: col=lane&15, row=(lane>>4)*4+reg  [m89-verified]
  const int crow = (lane >> 4) * 4, ccol = lane & 15;
  __syncthreads();
  if (half == 1) {
#pragma unroll
    for (int mt = 0; mt < 2; ++mt)
#pragma unroll
      for (int nt = 0; nt < 4; ++nt)
#pragma unroll
        for (int r = 0; r < 4; ++r)
          Cred[(m0 + mt * 16 + crow + r) * 132 + n0 + nt * 16 + ccol] = acc[mt][nt][r];
  }
  __syncthreads();
  if (half == 0) {
    const float invn = 1.0f / 2048.0f;
#pragma unroll
    for (int mt = 0; mt < 2; ++mt)
#pragma unroll
      for (int nt = 0; nt < 4; ++nt) {
        const int gi0 = row0 + m0 + mt * 16 + crow;
        const int gj = col0 + n0 + nt * 16 + ccol;
        size_t base = (size_t)gi0 * 2048 + gj;
#pragma unroll
        for (int r = 0; r < 4; ++r) {
          const int li = (m0 + mt * 16 + crow + r) * 132 + n0 + nt * 16 + ccol;
          float val = (acc[mt][nt][r] + Cred[li]) * invn +
                      ((gi0 + r == gj) ? 1.0f : 0.0f);
          M[base + (size_t)r * 2048] = val;
          if (!diag) Cred[li] = val;        // park final value for mirror pass
        }
      }
  }
  if (!diag) {
    __syncthreads();                         // Cred holds the final fp32 tile
    const int orow = tid >> 2;               // 0..127 (original tile col)
    const int cseg = (tid & 3) * 16;         // 0..48  (original tile row base)
    float mv[16];
#pragma unroll
    for (int k = 0; k < 16; ++k)
      mv[k] = Cred[(cseg + k) * 132 + orow];
    float4* dst = (float4*)(M + (size_t)(col0 + orow) * 2048 + row0 + cseg);
    dst[0] = (float4){mv[0], mv[1], mv[2], mv[3]};
    dst[1] = (float4){mv[4], mv[5], mv[6], mv[7]};
    dst[2] = (float4){mv[8], mv[9], mv[10], mv[11]};
    dst[3] = (float4){mv[12], mv[13], mv[14], mv[15]};
  }
}

// ---- deterministic block-wide sum over 8 waves: bitwise-identical per block ----
__device__ __forceinline__ float block_sum8(float v, float* red) {
#pragma unroll
  for (int off = 32; off; off >>= 1) v += __shfl_down(v, off);
  if ((threadIdx.x & 63) == 0) red[threadIdx.x >> 6] = v;
  __syncthreads();
  float r = ((red[0] + red[1]) + (red[2] + red[3])) +
            ((red[4] + red[5]) + (red[6] + red[7]));
  __syncthreads();
  return r;
}

// ---- 5. Lanczos: single-phase epoch protocol, 128 x 512 — FROZEN core (R20) ----
// R20: ~4.2 us/iter exchange is the store->remote-observability floor.
// RULE 1 (R1/R6): cross-block data via agent-scope atomics only.
// RULE 2 (R1/R6/R8): beta^2 = ||z - alpha v||^2 DIRECT form only.
// RULE 3 (R16): no fixed-address staging reuse with plain cached loads.
// RULE 4 (R17): exactly ONE publish->consume phase per iteration.
// RULE 5 (R19/R20): exchange cost is per-phase visibility latency.
// NEW (R29): sparse term S + S^T + SS^T applied to this block's 16 staged
// rows via LDS atomicAdd (between two barriers, before the iteration loop).
// Within-block add order is nondet (last-ulp) but each Z row has a single
// producer, so all consumers see identical values — block-redundant scalar
// invariant intact.
__global__ __launch_bounds__(512) void lanczos_kernel(const float* __restrict__ M,
                                                      const unsigned* __restrict__ cntR,
                                                      const int* __restrict__ binRc,
                                                      const float* __restrict__ binRv,
                                                      const unsigned* __restrict__ cntC,
                                                      const int* __restrict__ binCr,
                                                      const float* __restrict__ binCv,
                                                      unsigned long long* __restrict__ Z0,
                                                      unsigned long long* __restrict__ Z1,
                                                      float* __restrict__ out) {
  const int tid = threadIdx.x, b = blockIdx.x;
  const int wave = tid >> 6, lane = tid & 63;
  __shared__ __align__(16) float Mlds[16 * 2048];  // 128 KB: this block's 16 rows
  __shared__ __align__(16) float VA[2048];
  __shared__ __align__(16) float VB[2048];
  __shared__ float red[8];
  __shared__ float al[LK + 2], b2[LK + 2];
  __shared__ float bnds[2], res[2];

  const float* Mblk = M + (size_t)b * 16 * 2048;
#pragma unroll
  for (int q = 0; q < 16; ++q)
    __builtin_amdgcn_global_load_lds(AS1C(Mblk + wave * 4096 + q * 256 + lane * 4),
                                     AS3(Mlds + wave * 4096 + q * 256), 16, 0, 0);

  // block-redundant init: v1 = hash / ||hash||  (identical in every block), v0 = 0
  float pv[4];
  float part = 0.f;
#pragma unroll
  for (int t = 0; t < 4; ++t) {
    int i = t * 512 + tid;
    unsigned u = (unsigned)i * 2654435761u;
    u ^= u >> 16; u *= 2246822519u; u ^= u >> 13;
    float rv = (float)(u >> 8) * (2.f / 16777216.f) - 1.f;
    pv[t] = rv;
    part += rv * rv;
  }
  float nrm = block_sum8(part, red);       // barriers inside drain Mlds staging
  float innm = rsqrtf(nrm);
#pragma unroll
  for (int t = 0; t < 4; ++t) {
    int i = t * 512 + tid;
    VA[i] = pv[t] * innm;
    VB[i] = 0.f;
  }
  __syncthreads();                         // Mlds fully staged; VA/VB ready

  // ---- R29: apply S + S^T + SS^T to this block's rows (LDS atomics) ----
  // wave handles its 2 rows: r = b*16 + wave*2 + rr.
  for (int rr = 0; rr < 2; ++rr) {
    const int r = b * 16 + wave * 2 + rr;
    float* Mrow = Mlds + (wave * 2 + rr) * 2048;
    const unsigned nR = min(cntR[r], (unsigned)BINCAP);
    // S: row bin r -> M[r, c] += v
    for (unsigned e = lane; e < nR; e += 64)
      atomicAdd(&Mrow[binRc[r * BINCAP + e]], binRv[r * BINCAP + e]);
    // S^T: column bin r -> M[r, j] += v   (entries (j, r, v) of S)
    const unsigned nC = min(cntC[r], (unsigned)BINCAP);
    for (unsigned e = lane; e < nC; e += 64)
      atomicAdd(&Mrow[binCr[r * BINCAP + e]], binCv[r * BINCAP + e]);
    // SS^T: for (r,c,v) in row bin r, for (j,v2) in column bin c: M[r,j]+=v*v2
    for (unsigned e = 0; e < nR; ++e) {
      const int c = binRc[r * BINCAP + e];
      const float v = binRv[r * BINCAP + e];
      const unsigned nc2 = min(cntC[c], (unsigned)BINCAP);
      for (unsigned p = lane; p < nc2; p += 64)
        atomicAdd(&Mrow[binCr[c * BINCAP + p]], v * binCv[c * BINCAP + p]);
    }
  }
  __syncthreads();                         // sparse apply complete

  float* Vcur = VA;
  float* Vprev = VB;
  float beta_prev = 0.f;

  for (int j = 1; j <= LK; ++j) {
    unsigned long long* Z = (j & 1) ? Z0 : Z1;
#pragma unroll
    for (int rr = 0; rr < 2; ++rr) {
      const int r = b * 16 + wave * 2 + rr;
      const float4* Mr = (const float4*)(Mlds + (wave * 2 + rr) * 2048);
      float s = 0.f;
#pragma unroll
      for (int t = 0; t < 8; ++t) {
        int idx = t * 64 + lane;
        float4 m4 = Mr[idx];
        float4 v4 = ((const float4*)Vcur)[idx];
        s += m4.x * v4.x + m4.y * v4.y + m4.z * v4.z + m4.w * v4.w;
      }
#pragma unroll
      for (int off = 32; off; off >>= 1) s += __shfl_down(s, off);
      if (lane == 0) {
        float zv = s - beta_prev * Vprev[r];
        unsigned long long pk = ((unsigned long long)(unsigned)j << 32) |
                                (unsigned long long)(unsigned)__float_as_uint(zv);
        __hip_atomic_store(&Z[r], pk, __ATOMIC_RELAXED, AGENT);
      }
    }

    // hoist own v-slice reads (LDS) ahead of the poll — free overlap
    float va[4];
#pragma unroll
    for (int t = 0; t < 4; ++t) va[t] = Vcur[t * 512 + tid];

    unsigned long long w4[4];
    int rounds = 0;
    for (;;) {
      bool ok = true;
#pragma unroll
      for (int t = 0; t < 4; ++t) {
        w4[t] = __hip_atomic_load(&Z[t * 512 + tid], __ATOMIC_RELAXED, AGENT);
        ok &= ((unsigned)(w4[t] >> 32) == (unsigned)j);
      }
      if (ok) break;
      if (rounds == 1)      __builtin_amdgcn_s_sleep(1);   //  64 clk
      else if (rounds == 2) __builtin_amdgcn_s_sleep(2);   // 128 clk
      else if (rounds >= 3) __builtin_amdgcn_s_sleep(8);   // 512 clk
      ++rounds;
    }
    float za[4];
    float pa = 0.f;
#pragma unroll
    for (int t = 0; t < 4; ++t) {
      za[t] = __uint_as_float((unsigned)w4[t]);
      pa += za[t] * va[t];
    }
    float alpha = block_sum8(pa, red);
    float pb = 0.f;
#pragma unroll
    for (int t = 0; t < 4; ++t) {
      float rsd = za[t] - alpha * va[t];
      pb += rsd * rsd;
    }
    float beta2 = block_sum8(pb, red);
    float beta = sqrtf(fmaxf(beta2, 1e-30f));
    float invb = 1.f / beta;
    if (tid == 0) { al[j] = alpha; b2[j] = beta2; }
#pragma unroll
    for (int t = 0; t < 4; ++t) {
      int i = t * 512 + tid;
      Vprev[i] = (za[t] - alpha * va[t]) * invb;
    }
    float* tmp = Vprev; Vprev = Vcur; Vcur = tmp;
    beta_prev = beta;
    __syncthreads();
  }

  // ---- extreme eigenvalues of T via Sturm bisection (block 0) ----
  if (b == 0) {
    if (tid == 0) {                                  // Gershgorin bounds on T
      float lo = 1e30f, hi = -1e30f;
      for (int i = 1; i <= LK; ++i) {
        float bl = (i > 1) ? sqrtf(b2[i - 1]) : 0.f;
        float br = (i < LK) ? sqrtf(b2[i]) : 0.f;
        lo = fminf(lo, al[i] - bl - br);
        hi = fmaxf(hi, al[i] + bl + br);
      }
      bnds[0] = lo; bnds[1] = hi;
    }
    __syncthreads();
    if (wave < 2) {                 // wave 0 -> lambda_min, wave 1 -> lambda_max
      const int tcount = (wave == 0) ? 1 : LK;
      float lo = bnds[0], hi = bnds[1];
      for (int round = 0; round < 4; ++round) {
        float x = lo + (hi - lo) * (float)(lane + 1) * (1.f / 65.f);
        int cnt = 0;                                 // #eigs of T below x
        float d = al[1] - x;
        if (fabsf(d) < 1e-25f) d = -1e-25f;
        if (d < 0.f) cnt++;
        for (int i = 2; i <= LK; ++i) {
          d = (al[i] - x) - b2[i - 1] / d;
          if (fabsf(d) < 1e-25f) d = -1e-25f;
          if (d < 0.f) cnt++;
        }
        bool ab = (cnt >= tcount);                   // x is above the target eig
        float cand_hi = ab ? x : hi;
        float cand_lo = ab ? lo : x;
#pragma unroll
        for (int off = 32; off; off >>= 1) {
          cand_hi = fminf(cand_hi, __shfl_down(cand_hi, off));
          cand_lo = fmaxf(cand_lo, __shfl_down(cand_lo, off));
        }
        cand_hi = __shfl(cand_hi, 0);
        cand_lo = __shfl(cand_lo, 0);
        hi = cand_hi;
        lo = fminf(cand_lo, hi);
      }
      if (lane == 0) res[wave] = 0.5f * (lo + hi);
    }
    __syncthreads();
    if (tid == 0) {
      float lmin = fmaxf(res[0], 1e-12f);
      float lmax = fmaxf(res[1], 1e-12f);
      out[0] = logf(lmax) - logf(lmin);
    }
  }
}

extern "C" void kernel_launch(void* const* d_in, const int* in_sizes, int n_in,
                              void* d_out, int out_size, void* d_ws, size_t ws_size,
                              hipStream_t stream) {
  const float* pred = (const float*)d_in[0];
  const float* scal = (const float*)d_in[1];
  const float* W    = (const float*)d_in[2];
  const int*   rows = (const int*)d_in[3];
  const int*   cols = (const int*)d_in[4];
  float* out = (float*)d_out;

  // workspace layout (peak ~34.2 MB):
  //  [0,8MB)   : Hf fp16
  //  [8,16MB)  : Gh fp16 (G = L*Wh)
  //  [16,32MB) : M fp32
  //  [32MB,..) : cntR 8KB | cntC 8KB | binRc 512KB | binRv 512KB |
  //              binCr 512KB | binCv 512KB | Z0 16KB | Z1 16KB
  char* ws = (char*)d_ws;
  const size_t MB = 1024 * 1024;
  unsigned short* Hf = (unsigned short*)(ws);
  unsigned short* Gh = (unsigned short*)(ws + 8 * MB);
  float* M = (float*)(ws + 16 * MB);
  char* ctrl = ws + 32 * MB;
  unsigned* cntR = (unsigned*)(ctrl);
  unsigned* cntC = (unsigned*)(ctrl + 8192);
  int*      binRc = (int*)(ctrl + 16384);
  float*    binRv = (float*)(ctrl + 16384 + 524288);
  int*      binCr = (int*)(ctrl + 16384 + 2 * 524288);
  float*    binCv = (float*)(ctrl + 16384 + 3 * 524288);
  unsigned long long* Z0 = (unsigned long long*)(ctrl + 16384 + 4 * 524288);
  unsigned long long* Z1 = (unsigned long long*)(ctrl + 16384 + 4 * 524288 + 16384);

  convert_kernel<<<4096, 256, 0, stream>>>(W, Hf, cntR, cntC);
  fill_kernel<<<NNZ / 256, 256, 0, stream>>>(pred, scal, rows, cols,
                                             cntR, binRc, binRv, cntC, binCr, binCv);
  gatherG_kernel<<<2048, 256, 0, stream>>>(cntR, binRc, binRv, Hf, Gh);  // G = L*Wh
  gemmM_kernel<<<272, 512, 0, stream>>>(Gh, M);                          // M = GG^T/N + I
  // sparse term S + S^T + SS^T applied inside lanczos (LDS, per-block rows)
  lanczos_kernel<<<NBL, 512, 0, stream>>>(M, cntR, binRc, binRv,
                                          cntC, binCr, binCv, Z0, Z1, out);
}

// Round 15
// 249.062 us; speedup vs baseline: 1.0738x; 1.0738x over previous
//
#include <hip/hip_runtime.h>

// Problem constants (fixed by the reference)
#define N2 2048
#define NNZ 32768
#define LK 22          // FROZEN: absmax 0.0234 of 0.037 threshold (3 of ~4.7 bf16 ulps)
#define NBL 128        // lanczos grid blocks: 128 x 512 thr; 147KB LDS -> 1 block/CU
#define BINCAP 64      // slots per bin (Poisson(16) tail ~1e-15)
#define LCAP 768       // packed per-row list capacity (E[n]=288, Poisson tail ~0)

typedef __attribute__((ext_vector_type(8))) _Float16 half8;
typedef __attribute__((ext_vector_type(4))) float f32x4;

#define AGENT __HIP_MEMORY_SCOPE_AGENT
#define AS1C(p) ((const __attribute__((address_space(1))) unsigned int*)(p))
#define AS3(p)  ((__attribute__((address_space(3))) unsigned int*)(p))

__device__ __forceinline__ unsigned short f2h(float f) {
  _Float16 h = (_Float16)f;                   // fp16 RNE
  return *(unsigned short*)&h;
}

// ==== R30 pipeline:  M = L A L^T,  L = I + S,  A = WW^T/N + I
//   = (L Wh)(L Wh)^T / N + I   [dense: gatherG(35us) + symmetric GEMM(48us)]
//   + S + S^T + S S^T          [sparse: EXPANDED to packed per-row lists by a
//                               parallel kernel, applied in lanczos via
//                               coalesced reads + LDS atomicAdd]
// R14 ledger: non-lanczos 104.7us matched the model; the R29 in-lanczos apply
// cost 49us because its SS^T loop was a SERIAL dependent-load chain per wave
// (LDS->cntC->binC, ~16x3 dependent ~300ns loads, <=16/64 lanes active).
// expand_kernel does that traversal ONCE with full thread-parallelism.

// ---- 1. W (fp32) -> fp16; zero row/col bin counters ----
__global__ __launch_bounds__(256) void convert_kernel(const float* __restrict__ W,
                                                      unsigned short* __restrict__ Hf,
                                                      unsigned* __restrict__ cntR,
                                                      unsigned* __restrict__ cntC) {
  if (blockIdx.x < 8)       cntR[blockIdx.x * 256 + threadIdx.x] = 0;
  else if (blockIdx.x < 16) cntC[(blockIdx.x - 8) * 256 + threadIdx.x] = 0;
  int i4 = blockIdx.x * 256 + threadIdx.x;          // grid 4096 -> 1048576 float4s
  float4 w = ((const float4*)W)[i4];
  ushort4 h;
  h.x = f2h(w.x); h.y = f2h(w.y); h.z = f2h(w.z); h.w = f2h(w.w);
  ((ushort4*)Hf)[i4] = h;
}

// ---- 2. fill row bins (G-gather, SS^T) and column bins (S^T, SS^T) ----
__global__ __launch_bounds__(256) void fill_kernel(const float* __restrict__ pred,
                                                   const float* __restrict__ scal,
                                                   const int* __restrict__ rows,
                                                   const int* __restrict__ cols,
                                                   unsigned* __restrict__ cntR,
                                                   int* __restrict__ binRc,
                                                   float* __restrict__ binRv,
                                                   unsigned* __restrict__ cntC,
                                                   int* __restrict__ binCr,
                                                   float* __restrict__ binCv) {
  int k = blockIdx.x * 256 + threadIdx.x;
  int r = rows[k], c = cols[k];
  float v = pred[k] * scal[k];
  unsigned pR = atomicAdd(&cntR[r], 1u);
  if (pR < BINCAP) { binRc[r * BINCAP + pR] = c; binRv[r * BINCAP + pR] = v; }
  unsigned pC = atomicAdd(&cntC[c], 1u);
  if (pC < BINCAP) { binCr[c * BINCAP + pC] = r; binCv[c * BINCAP + pC] = v; }
}

// ---- 2b. expand row r's sparse contributions to a packed (col,val) list ----
// list r = { S: (c_e, v_e) } u { S^T: (r_e, v_e) from col bin r }
//        u { SS^T: for e in rowbin r, (j_p, v_e*v2_p) for p in colbin c_e }.
// All reads L2-hot; all parallelism across 256 threads (no serial dep chains).
__global__ __launch_bounds__(256) void expand_kernel(const unsigned* __restrict__ cntR,
                                                     const int* __restrict__ binRc,
                                                     const float* __restrict__ binRv,
                                                     const unsigned* __restrict__ cntC,
                                                     const int* __restrict__ binCr,
                                                     const float* __restrict__ binCv,
                                                     int* __restrict__ colList,
                                                     float* __restrict__ valList,
                                                     unsigned* __restrict__ listCnt) {
  const int r = blockIdx.x, tid = threadIdx.x;
  __shared__ int sc[BINCAP];
  __shared__ float sv[BINCAP];
  __shared__ unsigned ncc[BINCAP];
  __shared__ unsigned pre[BINCAP + 1];
  const unsigned nR = min(cntR[r], (unsigned)BINCAP);
  const unsigned nC = min(cntC[r], (unsigned)BINCAP);
  if (tid < nR) {
    sc[tid] = binRc[r * BINCAP + tid];
    sv[tid] = binRv[r * BINCAP + tid];
  }
  __syncthreads();
  if (tid < nR) ncc[tid] = min(cntC[sc[tid]], (unsigned)BINCAP);  // parallel loads
  __syncthreads();
  if (tid == 0) {
    pre[0] = 0;
    for (unsigned e = 0; e < nR; ++e) pre[e + 1] = pre[e] + ncc[e];  // LDS-only
  }
  __syncthreads();
  const unsigned base = nR + nC;
  const unsigned total = base + pre[nR];
  if (tid == 0) listCnt[r] = min(total, (unsigned)LCAP);
  int* cl = colList + (size_t)r * LCAP;
  float* vl = valList + (size_t)r * LCAP;
  if (tid < nR) { cl[tid] = sc[tid]; vl[tid] = sv[tid]; }            // S
  if (tid < nC && nR + tid < LCAP) {                                 // S^T
    cl[nR + tid] = binCr[r * BINCAP + tid];
    vl[nR + tid] = binCv[r * BINCAP + tid];
  }
  const unsigned np = pre[nR];
  for (unsigned p = tid; p < np; p += 256) {                         // SS^T
    unsigned e = 0;
    while (pre[e + 1] <= p) ++e;                 // nR<=64, LDS linear scan
    const int c = sc[e];
    const unsigned q = p - pre[e];
    const unsigned idx = base + p;
    if (idx < LCAP) {
      cl[idx] = binCr[c * BINCAP + q];
      vl[idx] = sv[e] * binCv[c * BINCAP + q];
    }
  }
}

// ---- 3. G[r,:] = Hf[r,:] + sum_e v_e * Hf[c_e,:]  (fp16 out, fp32 acc, MLP-8) ----
__global__ __launch_bounds__(256) void gatherG_kernel(const unsigned* __restrict__ cntR,
                                                      const int* __restrict__ binRc,
                                                      const float* __restrict__ binRv,
                                                      const unsigned short* __restrict__ Hf,
                                                      unsigned short* __restrict__ Gh) {
  const int r = blockIdx.x, tid = threadIdx.x;
  __shared__ int scol_[BINCAP];
  __shared__ float sval_[BINCAP];
  const unsigned ne = min(cntR[r], (unsigned)BINCAP);
  if (tid < ne) {
    scol_[tid] = binRc[r * BINCAP + tid];
    sval_[tid] = binRv[r * BINCAP + tid];
  }
  __syncthreads();
  // init from own row (the I in L = I + S)
  uint4 own = *(const uint4*)(Hf + (size_t)r * 2048 + tid * 8);
  half8 ho = *(half8*)&own;
  float acc[8];
#pragma unroll
  for (int k = 0; k < 8; ++k) acc[k] = (float)ho[k];
  unsigned e = 0;
  for (; e + 8 <= ne; e += 8) {
    uint4 q[8];
#pragma unroll
    for (int u = 0; u < 8; ++u)
      q[u] = *(const uint4*)(Hf + (size_t)scol_[e + u] * 2048 + tid * 8);
#pragma unroll
    for (int u = 0; u < 8; ++u) {
      half8 hv = *(half8*)&q[u];
      const float v = sval_[e + u];
#pragma unroll
      for (int k = 0; k < 8; ++k) acc[k] += v * (float)hv[k];
    }
  }
  for (; e + 4 <= ne; e += 4) {
    uint4 q[4];
#pragma unroll
    for (int u = 0; u < 4; ++u)
      q[u] = *(const uint4*)(Hf + (size_t)scol_[e + u] * 2048 + tid * 8);
#pragma unroll
    for (int u = 0; u < 4; ++u) {
      half8 hv = *(half8*)&q[u];
      const float v = sval_[e + u];
#pragma unroll
      for (int k = 0; k < 8; ++k) acc[k] += v * (float)hv[k];
    }
  }
  for (; e < ne; ++e) {
    uint4 qq = *(const uint4*)(Hf + (size_t)scol_[e] * 2048 + tid * 8);
    half8 hv = *(half8*)&qq;
    const float v = sval_[e];
#pragma unroll
    for (int k = 0; k < 8; ++k) acc[k] += v * (float)hv[k];
  }
  unsigned short o[8];
#pragma unroll
  for (int k = 0; k < 8; ++k) o[k] = f2h(acc[k]);
  *(uint4*)(Gh + (size_t)r * 2048 + tid * 8) = *(uint4*)o;
}

// ---- 4. M = G*G^T/N + I — symmetric-half (R23) + dbuf split-K (R24), fp32 out ----
__device__ __forceinline__ void stage_tiles2(const unsigned short* __restrict__ X,
                                             unsigned short* Xb, unsigned short* Yb,
                                             int row0, int col0, int kk,
                                             int srowX, int srowY, int scol, int wq) {
  __builtin_amdgcn_global_load_lds(
      AS1C(X + (size_t)(row0 + srowX) * 2048 + kk + scol),
      AS3(Xb + (wq * 16) * 32), 16, 0, 0);
#pragma unroll
  for (int q = 0; q < 2; ++q) {
    __builtin_amdgcn_global_load_lds(
        AS1C(X + (size_t)(col0 + srowY + q * 16) * 2048 + kk + scol),
        AS3(Yb + (wq * 32 + q * 16) * 32), 16, 0, 0);
  }
}

__global__ __launch_bounds__(512) void gemmM_kernel(const unsigned short* __restrict__ Gh,
                                                    float* __restrict__ M) {
  const int tid = threadIdx.x;
  // tile mapping: 32 diag-band + 240 pure-lower (R23)
  int bi, bj;
  bool diag;
  if (blockIdx.x < 32) {
    bi = blockIdx.x; bj = bi >> 1; diag = true;
  } else {
    int idx = blockIdx.x - 32;                // 0..239
    int j = 0;                                 // off(j) = j*(31-j)
    while (j < 14 && idx >= (j + 1) * (30 - j)) ++j;
    bj = j;
    bi = 2 * j + 2 + (idx - j * (31 - j));
    diag = false;
  }

  __shared__ __align__(16) char smem[49152];   // 48KB staging; Cred aliases after
  unsigned short* Xs = (unsigned short*)smem;             // [half][buf][64*32]
  unsigned short* Ys = (unsigned short*)(smem + 16384);   // [half][buf][128*32]
  float* Cred = (float*)smem;                             // [64*132] post-loop

  const int w = tid >> 6, lane = tid & 63;
  const int half = w >> 2, wq = w & 3;      // k-half, role within half
  const int row0 = bi * 64, col0 = bj * 128;
  const int m0 = (wq & 1) * 32, n0 = (wq >> 1) * 64;
  f32x4 acc[2][4];
#pragma unroll
  for (int a = 0; a < 2; ++a)
#pragma unroll
    for (int b = 0; b < 4; ++b) acc[a][b] = (f32x4){0.f, 0.f, 0.f, 0.f};
  const int mrow = lane & 15, kseg = (lane >> 4) * 8;
  const int srowX = wq * 16 + (lane >> 2);
  const int srowY = wq * 32 + (lane >> 2);
  const int scol = (lane & 3) * 8;
  const int kbase = half * 1024;

  stage_tiles2(Gh, Xs + (half * 2 + 0) * 2048, Ys + (half * 2 + 0) * 4096,
               row0, col0, kbase, srowX, srowY, scol, wq);
  for (int t = 0; t < 32; ++t) {
    const int cur = t & 1;
    __syncthreads();
    if (t < 31)
      stage_tiles2(Gh, Xs + (half * 2 + (cur ^ 1)) * 2048,
                   Ys + (half * 2 + (cur ^ 1)) * 4096,
                   row0, col0, kbase + (t + 1) * 32, srowX, srowY, scol, wq);
    const unsigned short* Xb = Xs + (half * 2 + cur) * 2048;
    const unsigned short* Yb = Ys + (half * 2 + cur) * 4096;
    half8 af[2], bf[4];
#pragma unroll
    for (int q = 0; q < 2; ++q)
      af[q] = *(const half8*)(Xb + (m0 + q * 16 + mrow) * 32 + kseg);
#pragma unroll
    for (int q = 0; q < 4; ++q)
      bf[q] = *(const half8*)(Yb + (n0 + q * 16 + mrow) * 32 + kseg);
#pragma unroll
    for (int mt = 0; mt < 2; ++mt)
#pragma unroll
      for (int nt = 0; nt < 4; ++nt)
        acc[mt][nt] = __builtin_amdgcn_mfma_f32_16x16x32_f16(af[mt], bf[nt], acc[mt][nt], 0, 0, 0);
  }
  // combine halves; epilogue applies /N + I; fp32 direct + fp32 mirror.
  // C/D layout: col=lane&15, row=(lane>>4)*4+reg  [m89-verified]
  const int crow = (lane >> 4) * 4, ccol = lane & 15;
  __syncthreads();
  if (half == 1) {
#pragma unroll
    for (int mt = 0; mt < 2; ++mt)
#pragma unroll
      for (int nt = 0; nt < 4; ++nt)
#pragma unroll
        for (int r = 0; r < 4; ++r)
          Cred[(m0 + mt * 16 + crow + r) * 132 + n0 + nt * 16 + ccol] = acc[mt][nt][r];
  }
  __syncthreads();
  if (half == 0) {
    const float invn = 1.0f / 2048.0f;
#pragma unroll
    for (int mt = 0; mt < 2; ++mt)
#pragma unroll
      for (int nt = 0; nt < 4; ++nt) {
        const int gi0 = row0 + m0 + mt * 16 + crow;
        const int gj = col0 + n0 + nt * 16 + ccol;
        size_t base = (size_t)gi0 * 2048 + gj;
#pragma unroll
        for (int r = 0; r < 4; ++r) {
          const int li = (m0 + mt * 16 + crow + r) * 132 + n0 + nt * 16 + ccol;
          float val = (acc[mt][nt][r] + Cred[li]) * invn +
                      ((gi0 + r == gj) ? 1.0f : 0.0f);
          M[base + (size_t)r * 2048] = val;
          if (!diag) Cred[li] = val;        // park final value for mirror pass
        }
      }
  }
  if (!diag) {
    __syncthreads();                         // Cred holds the final fp32 tile
    const int orow = tid >> 2;               // 0..127 (original tile col)
    const int cseg = (tid & 3) * 16;         // 0..48  (original tile row base)
    float mv[16];
#pragma unroll
    for (int k = 0; k < 16; ++k)
      mv[k] = Cred[(cseg + k) * 132 + orow];
    float4* dst = (float4*)(M + (size_t)(col0 + orow) * 2048 + row0 + cseg);
    dst[0] = (float4){mv[0], mv[1], mv[2], mv[3]};
    dst[1] = (float4){mv[4], mv[5], mv[6], mv[7]};
    dst[2] = (float4){mv[8], mv[9], mv[10], mv[11]};
    dst[3] = (float4){mv[12], mv[13], mv[14], mv[15]};
  }
}

// ---- deterministic block-wide sum over 8 waves: bitwise-identical per block ----
__device__ __forceinline__ float block_sum8(float v, float* red) {
#pragma unroll
  for (int off = 32; off; off >>= 1) v += __shfl_down(v, off);
  if ((threadIdx.x & 63) == 0) red[threadIdx.x >> 6] = v;
  __syncthreads();
  float r = ((red[0] + red[1]) + (red[2] + red[3])) +
            ((red[4] + red[5]) + (red[6] + red[7]));
  __syncthreads();
  return r;
}

// ---- 5. Lanczos: single-phase epoch protocol, 128 x 512 — FROZEN core (R20) ----
// R20: ~4.2 us/iter exchange is the store->remote-observability floor.
// RULE 1 (R1/R6): cross-block data via agent-scope atomics only.
// RULE 2 (R1/R6/R8): beta^2 = ||z - alpha v||^2 DIRECT form only.
// RULE 3 (R16): no fixed-address staging reuse with plain cached loads.
// RULE 4 (R17): exactly ONE publish->consume phase per iteration.
// RULE 5 (R19/R20): exchange cost is per-phase visibility latency.
// RULE 6 (R14/R30): NO serial dependent-load chains in-kernel — sparse apply
// now reads PRE-EXPANDED packed lists (coalesced, independent) + LDS atomics.
// Single producer per Z row -> block-redundant scalar invariant intact.
__global__ __launch_bounds__(512) void lanczos_kernel(const float* __restrict__ M,
                                                      const unsigned* __restrict__ listCnt,
                                                      const int* __restrict__ colList,
                                                      const float* __restrict__ valList,
                                                      unsigned long long* __restrict__ Z0,
                                                      unsigned long long* __restrict__ Z1,
                                                      float* __restrict__ out) {
  const int tid = threadIdx.x, b = blockIdx.x;
  const int wave = tid >> 6, lane = tid & 63;
  __shared__ __align__(16) float Mlds[16 * 2048];  // 128 KB: this block's 16 rows
  __shared__ __align__(16) float VA[2048];
  __shared__ __align__(16) float VB[2048];
  __shared__ float red[8];
  __shared__ float al[LK + 2], b2[LK + 2];
  __shared__ float bnds[2], res[2];

  const float* Mblk = M + (size_t)b * 16 * 2048;
#pragma unroll
  for (int q = 0; q < 16; ++q)
    __builtin_amdgcn_global_load_lds(AS1C(Mblk + wave * 4096 + q * 256 + lane * 4),
                                     AS3(Mlds + wave * 4096 + q * 256), 16, 0, 0);

  // block-redundant init: v1 = hash / ||hash||  (identical in every block), v0 = 0
  float pv[4];
  float part = 0.f;
#pragma unroll
  for (int t = 0; t < 4; ++t) {
    int i = t * 512 + tid;
    unsigned u = (unsigned)i * 2654435761u;
    u ^= u >> 16; u *= 2246822519u; u ^= u >> 13;
    float rv = (float)(u >> 8) * (2.f / 16777216.f) - 1.f;
    pv[t] = rv;
    part += rv * rv;
  }
  float nrm = block_sum8(part, red);       // barriers inside drain Mlds staging
  float innm = rsqrtf(nrm);
#pragma unroll
  for (int t = 0; t < 4; ++t) {
    int i = t * 512 + tid;
    VA[i] = pv[t] * innm;
    VB[i] = 0.f;
  }
  __syncthreads();                         // Mlds fully staged; VA/VB ready

  // ---- R30: apply packed sparse lists to this block's rows (coalesced) ----
  for (int rr = 0; rr < 2; ++rr) {
    const int r = b * 16 + wave * 2 + rr;
    float* Mrow = Mlds + (wave * 2 + rr) * 2048;
    const unsigned n = min(listCnt[r], (unsigned)LCAP);
    const int* cl = colList + (size_t)r * LCAP;
    const float* vl = valList + (size_t)r * LCAP;
    for (unsigned i = lane; i < n; i += 64)
      atomicAdd(&Mrow[cl[i]], vl[i]);
  }
  __syncthreads();                         // sparse apply complete

  float* Vcur = VA;
  float* Vprev = VB;
  float beta_prev = 0.f;

  for (int j = 1; j <= LK; ++j) {
    unsigned long long* Z = (j & 1) ? Z0 : Z1;
#pragma unroll
    for (int rr = 0; rr < 2; ++rr) {
      const int r = b * 16 + wave * 2 + rr;
      const float4* Mr = (const float4*)(Mlds + (wave * 2 + rr) * 2048);
      float s = 0.f;
#pragma unroll
      for (int t = 0; t < 8; ++t) {
        int idx = t * 64 + lane;
        float4 m4 = Mr[idx];
        float4 v4 = ((const float4*)Vcur)[idx];
        s += m4.x * v4.x + m4.y * v4.y + m4.z * v4.z + m4.w * v4.w;
      }
#pragma unroll
      for (int off = 32; off; off >>= 1) s += __shfl_down(s, off);
      if (lane == 0) {
        float zv = s - beta_prev * Vprev[r];
        unsigned long long pk = ((unsigned long long)(unsigned)j << 32) |
                                (unsigned long long)(unsigned)__float_as_uint(zv);
        __hip_atomic_store(&Z[r], pk, __ATOMIC_RELAXED, AGENT);
      }
    }

    // hoist own v-slice reads (LDS) ahead of the poll — free overlap
    float va[4];
#pragma unroll
    for (int t = 0; t < 4; ++t) va[t] = Vcur[t * 512 + tid];

    unsigned long long w4[4];
    int rounds = 0;
    for (;;) {
      bool ok = true;
#pragma unroll
      for (int t = 0; t < 4; ++t) {
        w4[t] = __hip_atomic_load(&Z[t * 512 + tid], __ATOMIC_RELAXED, AGENT);
        ok &= ((unsigned)(w4[t] >> 32) == (unsigned)j);
      }
      if (ok) break;
      if (rounds == 1)      __builtin_amdgcn_s_sleep(1);   //  64 clk
      else if (rounds == 2) __builtin_amdgcn_s_sleep(2);   // 128 clk
      else if (rounds >= 3) __builtin_amdgcn_s_sleep(8);   // 512 clk
      ++rounds;
    }
    float za[4];
    float pa = 0.f;
#pragma unroll
    for (int t = 0; t < 4; ++t) {
      za[t] = __uint_as_float((unsigned)w4[t]);
      pa += za[t] * va[t];
    }
    float alpha = block_sum8(pa, red);
    float pb = 0.f;
#pragma unroll
    for (int t = 0; t < 4; ++t) {
      float rsd = za[t] - alpha * va[t];
      pb += rsd * rsd;
    }
    float beta2 = block_sum8(pb, red);
    float beta = sqrtf(fmaxf(beta2, 1e-30f));
    float invb = 1.f / beta;
    if (tid == 0) { al[j] = alpha; b2[j] = beta2; }
#pragma unroll
    for (int t = 0; t < 4; ++t) {
      int i = t * 512 + tid;
      Vprev[i] = (za[t] - alpha * va[t]) * invb;
    }
    float* tmp = Vprev; Vprev = Vcur; Vcur = tmp;
    beta_prev = beta;
    __syncthreads();
  }

  // ---- extreme eigenvalues of T via Sturm bisection (block 0) ----
  if (b == 0) {
    if (tid == 0) {                                  // Gershgorin bounds on T
      float lo = 1e30f, hi = -1e30f;
      for (int i = 1; i <= LK; ++i) {
        float bl = (i > 1) ? sqrtf(b2[i - 1]) : 0.f;
        float br = (i < LK) ? sqrtf(b2[i]) : 0.f;
        lo = fminf(lo, al[i] - bl - br);
        hi = fmaxf(hi, al[i] + bl + br);
      }
      bnds[0] = lo; bnds[1] = hi;
    }
    __syncthreads();
    if (wave < 2) {                 // wave 0 -> lambda_min, wave 1 -> lambda_max
      const int tcount = (wave == 0) ? 1 : LK;
      float lo = bnds[0], hi = bnds[1];
      for (int round = 0; round < 4; ++round) {
        float x = lo + (hi - lo) * (float)(lane + 1) * (1.f / 65.f);
        int cnt = 0;                                 // #eigs of T below x
        float d = al[1] - x;
        if (fabsf(d) < 1e-25f) d = -1e-25f;
        if (d < 0.f) cnt++;
        for (int i = 2; i <= LK; ++i) {
          d = (al[i] - x) - b2[i - 1] / d;
          if (fabsf(d) < 1e-25f) d = -1e-25f;
          if (d < 0.f) cnt++;
        }
        bool ab = (cnt >= tcount);                   // x is above the target eig
        float cand_hi = ab ? x : hi;
        float cand_lo = ab ? lo : x;
#pragma unroll
        for (int off = 32; off; off >>= 1) {
          cand_hi = fminf(cand_hi, __shfl_down(cand_hi, off));
          cand_lo = fmaxf(cand_lo, __shfl_down(cand_lo, off));
        }
        cand_hi = __shfl(cand_hi, 0);
        cand_lo = __shfl(cand_lo, 0);
        hi = cand_hi;
        lo = fminf(cand_lo, hi);
      }
      if (lane == 0) res[wave] = 0.5f * (lo + hi);
    }
    __syncthreads();
    if (tid == 0) {
      float lmin = fmaxf(res[0], 1e-12f);
      float lmax = fmaxf(res[1], 1e-12f);
      out[0] = logf(lmax) - logf(lmin);
    }
  }
}

extern "C" void kernel_launch(void* const* d_in, const int* in_sizes, int n_in,
                              void* d_out, int out_size, void* d_ws, size_t ws_size,
                              hipStream_t stream) {
  const float* pred = (const float*)d_in[0];
  const float* scal = (const float*)d_in[1];
  const float* W    = (const float*)d_in[2];
  const int*   rows = (const int*)d_in[3];
  const int*   cols = (const int*)d_in[4];
  float* out = (float*)d_out;

  // workspace layout (peak ~46.2 MB):
  //  [0,8MB)   : Hf fp16
  //  [8,16MB)  : Gh fp16 (G = L*Wh)
  //  [16,32MB) : M fp32
  //  [32,38MB) : colList int  (2048 x 768)
  //  [38,44MB) : valList f32  (2048 x 768)
  //  [44MB,..) : cntR 8KB | cntC 8KB | binRc 512KB | binRv 512KB |
  //              binCr 512KB | binCv 512KB | listCnt 8KB | Z0 16KB | Z1 16KB
  char* ws = (char*)d_ws;
  const size_t MB = 1024 * 1024;
  unsigned short* Hf = (unsigned short*)(ws);
  unsigned short* Gh = (unsigned short*)(ws + 8 * MB);
  float* M = (float*)(ws + 16 * MB);
  int*   colList = (int*)(ws + 32 * MB);
  float* valList = (float*)(ws + 38 * MB);
  char* ctrl = ws + 44 * MB;
  unsigned* cntR = (unsigned*)(ctrl);
  unsigned* cntC = (unsigned*)(ctrl + 8192);
  int*      binRc = (int*)(ctrl + 16384);
  float*    binRv = (float*)(ctrl + 16384 + 524288);
  int*      binCr = (int*)(ctrl + 16384 + 2 * 524288);
  float*    binCv = (float*)(ctrl + 16384 + 3 * 524288);
  unsigned* listCnt = (unsigned*)(ctrl + 16384 + 4 * 524288);
  unsigned long long* Z0 = (unsigned long long*)(ctrl + 16384 + 4 * 524288 + 8192);
  unsigned long long* Z1 = (unsigned long long*)(ctrl + 16384 + 4 * 524288 + 8192 + 16384);

  convert_kernel<<<4096, 256, 0, stream>>>(W, Hf, cntR, cntC);
  fill_kernel<<<NNZ / 256, 256, 0, stream>>>(pred, scal, rows, cols,
                                             cntR, binRc, binRv, cntC, binCr, binCv);
  expand_kernel<<<2048, 256, 0, stream>>>(cntR, binRc, binRv, cntC, binCr, binCv,
                                          colList, valList, listCnt);
  gatherG_kernel<<<2048, 256, 0, stream>>>(cntR, binRc, binRv, Hf, Gh);  // G = L*Wh
  gemmM_kernel<<<272, 512, 0, stream>>>(Gh, M);                          // M = GG^T/N + I
  lanczos_kernel<<<NBL, 512, 0, stream>>>(M, listCnt, colList, valList,
                                          Z0, Z1, out);
}

// Round 16
// 245.993 us; speedup vs baseline: 1.0872x; 1.0125x over previous
//
#include <hip/hip_runtime.h>

// Problem constants (fixed by the reference)
#define N2 2048
#define NNZ 32768
#define LK 22          // FROZEN: absmax 0.0234 of 0.037 threshold (3 of ~4.7 bf16 ulps)
#define NBL 128        // lanczos grid blocks: 128 x 512 thr; 147KB LDS -> 1 block/CU
#define BINCAP 64      // slots per bin (Poisson(16) tail ~1e-15)
#define LCAP 768       // packed per-row list capacity (E[n]=288, Poisson tail ~0)

typedef __attribute__((ext_vector_type(8))) _Float16 half8;
typedef __attribute__((ext_vector_type(4))) float f32x4;

#define AGENT __HIP_MEMORY_SCOPE_AGENT
#define AS1C(p) ((const __attribute__((address_space(1))) unsigned int*)(p))
#define AS3(p)  ((__attribute__((address_space(3))) unsigned int*)(p))

__device__ __forceinline__ unsigned short f2h(float f) {
  _Float16 h = (_Float16)f;                   // fp16 RNE
  return *(unsigned short*)&h;
}

// ==== R31 pipeline:  M = L A L^T,  L = I + S,  A = WW^T/N + I
//   = (L Wh)(L Wh)^T / N + I   [dense: gatherG(~35us) + symmetric GEMM(~48us)]
//   + S + S^T + S S^T          [sparse: packed per-row lists -> LDS apply]
// R15 ledger: expand cost ~23us (model said 4-6) — TWO serial LDS-dependent
// chains (thread-0 prefix; per-element while-search), each ~16 x 120cyc
// (m117 LDS latency) x 8 blocks/CU. RULE 6 extended: no dependent-load
// chains ANYWHERE, LDS included. R31 expand: wave-shuffle prefix scan
// (register-only) + group-parallel expansion (no search).

// ---- 1. W (fp32) -> fp16; zero row/col bin counters ----
__global__ __launch_bounds__(256) void convert_kernel(const float* __restrict__ W,
                                                      unsigned short* __restrict__ Hf,
                                                      unsigned* __restrict__ cntR,
                                                      unsigned* __restrict__ cntC) {
  if (blockIdx.x < 8)       cntR[blockIdx.x * 256 + threadIdx.x] = 0;
  else if (blockIdx.x < 16) cntC[(blockIdx.x - 8) * 256 + threadIdx.x] = 0;
  int i4 = blockIdx.x * 256 + threadIdx.x;          // grid 4096 -> 1048576 float4s
  float4 w = ((const float4*)W)[i4];
  ushort4 h;
  h.x = f2h(w.x); h.y = f2h(w.y); h.z = f2h(w.z); h.w = f2h(w.w);
  ((ushort4*)Hf)[i4] = h;
}

// ---- 2. fill row bins (G-gather, SS^T) and column bins (S^T, SS^T) ----
__global__ __launch_bounds__(256) void fill_kernel(const float* __restrict__ pred,
                                                   const float* __restrict__ scal,
                                                   const int* __restrict__ rows,
                                                   const int* __restrict__ cols,
                                                   unsigned* __restrict__ cntR,
                                                   int* __restrict__ binRc,
                                                   float* __restrict__ binRv,
                                                   unsigned* __restrict__ cntC,
                                                   int* __restrict__ binCr,
                                                   float* __restrict__ binCv) {
  int k = blockIdx.x * 256 + threadIdx.x;
  int r = rows[k], c = cols[k];
  float v = pred[k] * scal[k];
  unsigned pR = atomicAdd(&cntR[r], 1u);
  if (pR < BINCAP) { binRc[r * BINCAP + pR] = c; binRv[r * BINCAP + pR] = v; }
  unsigned pC = atomicAdd(&cntC[c], 1u);
  if (pC < BINCAP) { binCr[c * BINCAP + pC] = r; binCv[c * BINCAP + pC] = v; }
}

// ---- 2b. expand row r's sparse contributions to a packed (col,val) list ----
// list r = { S: (c_e, v_e) } u { S^T: (r_e, v_e) from col bin r }
//        u { SS^T: for e in rowbin r, (j_p, v_e*v2_p) for p in colbin c_e }.
// R31: wave-0 shuffle prefix scan (registers, 6 steps) + group-parallel
// expansion (16 threads per row-bin entry) — NO dependent-load chains.
// List order differs from R30 but apply is atomicAdd => same sums (last ulp).
__global__ __launch_bounds__(256) void expand_kernel(const unsigned* __restrict__ cntR,
                                                     const int* __restrict__ binRc,
                                                     const float* __restrict__ binRv,
                                                     const unsigned* __restrict__ cntC,
                                                     const int* __restrict__ binCr,
                                                     const float* __restrict__ binCv,
                                                     int* __restrict__ colList,
                                                     float* __restrict__ valList,
                                                     unsigned* __restrict__ listCnt) {
  const int r = blockIdx.x, tid = threadIdx.x;
  __shared__ int sc[BINCAP];
  __shared__ float sv[BINCAP];
  __shared__ unsigned ncc_[BINCAP];
  __shared__ unsigned pre_[BINCAP];          // exclusive prefix of ncc
  const unsigned nR = min(cntR[r], (unsigned)BINCAP);
  const unsigned nC = min(cntC[r], (unsigned)BINCAP);
  // wave 0: load row bin + colbin counts (independent loads), register scan
  if (tid < 64) {
    int c_ = 0; float v_ = 0.f; unsigned n_ = 0;
    if (tid < nR) {
      c_ = binRc[r * BINCAP + tid];
      v_ = binRv[r * BINCAP + tid];
      n_ = min(cntC[c_], (unsigned)BINCAP);
    }
    // inclusive shuffle scan over 64 lanes (register-only, 6 steps)
    unsigned x = n_;
#pragma unroll
    for (int off = 1; off < 64; off <<= 1) {
      unsigned t = __shfl_up(x, off);
      if (tid >= off) x += t;
    }
    sc[tid] = c_;
    sv[tid] = v_;
    ncc_[tid] = n_;
    pre_[tid] = x - n_;                      // exclusive prefix
    if (tid == 63) {
      unsigned total = nR + nC + x;          // x = full inclusive sum at lane 63
      listCnt[r] = min(total, (unsigned)LCAP);
    }
  }
  __syncthreads();
  int* cl = colList + (size_t)r * LCAP;
  float* vl = valList + (size_t)r * LCAP;
  if (tid < nR) { cl[tid] = sc[tid]; vl[tid] = sv[tid]; }            // S
  if (tid < nC && nR + tid < LCAP) {                                 // S^T
    cl[nR + tid] = binCr[r * BINCAP + tid];
    vl[nR + tid] = binCv[r * BINCAP + tid];
  }
  // SS^T: group g (16 threads) handles row-bin entry e=g; inner threads
  // write colbin-c_e products. All loads independent; no searches.
  const unsigned base0 = nR + nC;
  for (unsigned g = tid >> 4; g < nR; g += 16) {
    const int c = sc[g];
    const float v = sv[g];
    const unsigned n2 = ncc_[g];
    const unsigned base = base0 + pre_[g];
    for (unsigned p = tid & 15; p < n2; p += 16) {
      const unsigned idx = base + p;
      if (idx < LCAP) {
        cl[idx] = binCr[c * BINCAP + p];
        vl[idx] = v * binCv[c * BINCAP + p];
      }
    }
  }
}

// ---- 3. G[r,:] = Hf[r,:] + sum_e v_e * Hf[c_e,:]  (fp16 out, fp32 acc, MLP-8) ----
__global__ __launch_bounds__(256) void gatherG_kernel(const unsigned* __restrict__ cntR,
                                                      const int* __restrict__ binRc,
                                                      const float* __restrict__ binRv,
                                                      const unsigned short* __restrict__ Hf,
                                                      unsigned short* __restrict__ Gh) {
  const int r = blockIdx.x, tid = threadIdx.x;
  __shared__ int scol_[BINCAP];
  __shared__ float sval_[BINCAP];
  const unsigned ne = min(cntR[r], (unsigned)BINCAP);
  if (tid < ne) {
    scol_[tid] = binRc[r * BINCAP + tid];
    sval_[tid] = binRv[r * BINCAP + tid];
  }
  __syncthreads();
  // init from own row (the I in L = I + S)
  uint4 own = *(const uint4*)(Hf + (size_t)r * 2048 + tid * 8);
  half8 ho = *(half8*)&own;
  float acc[8];
#pragma unroll
  for (int k = 0; k < 8; ++k) acc[k] = (float)ho[k];
  unsigned e = 0;
  for (; e + 8 <= ne; e += 8) {
    uint4 q[8];
#pragma unroll
    for (int u = 0; u < 8; ++u)
      q[u] = *(const uint4*)(Hf + (size_t)scol_[e + u] * 2048 + tid * 8);
#pragma unroll
    for (int u = 0; u < 8; ++u) {
      half8 hv = *(half8*)&q[u];
      const float v = sval_[e + u];
#pragma unroll
      for (int k = 0; k < 8; ++k) acc[k] += v * (float)hv[k];
    }
  }
  for (; e + 4 <= ne; e += 4) {
    uint4 q[4];
#pragma unroll
    for (int u = 0; u < 4; ++u)
      q[u] = *(const uint4*)(Hf + (size_t)scol_[e + u] * 2048 + tid * 8);
#pragma unroll
    for (int u = 0; u < 4; ++u) {
      half8 hv = *(half8*)&q[u];
      const float v = sval_[e + u];
#pragma unroll
      for (int k = 0; k < 8; ++k) acc[k] += v * (float)hv[k];
    }
  }
  for (; e < ne; ++e) {
    uint4 qq = *(const uint4*)(Hf + (size_t)scol_[e] * 2048 + tid * 8);
    half8 hv = *(half8*)&qq;
    const float v = sval_[e];
#pragma unroll
    for (int k = 0; k < 8; ++k) acc[k] += v * (float)hv[k];
  }
  unsigned short o[8];
#pragma unroll
  for (int k = 0; k < 8; ++k) o[k] = f2h(acc[k]);
  *(uint4*)(Gh + (size_t)r * 2048 + tid * 8) = *(uint4*)o;
}

// ---- 4. M = G*G^T/N + I — symmetric-half (R23) + dbuf split-K (R24), fp32 out ----
__device__ __forceinline__ void stage_tiles2(const unsigned short* __restrict__ X,
                                             unsigned short* Xb, unsigned short* Yb,
                                             int row0, int col0, int kk,
                                             int srowX, int srowY, int scol, int wq) {
  __builtin_amdgcn_global_load_lds(
      AS1C(X + (size_t)(row0 + srowX) * 2048 + kk + scol),
      AS3(Xb + (wq * 16) * 32), 16, 0, 0);
#pragma unroll
  for (int q = 0; q < 2; ++q) {
    __builtin_amdgcn_global_load_lds(
        AS1C(X + (size_t)(col0 + srowY + q * 16) * 2048 + kk + scol),
        AS3(Yb + (wq * 32 + q * 16) * 32), 16, 0, 0);
  }
}

__global__ __launch_bounds__(512) void gemmM_kernel(const unsigned short* __restrict__ Gh,
                                                    float* __restrict__ M) {
  const int tid = threadIdx.x;
  // tile mapping: 32 diag-band + 240 pure-lower (R23)
  int bi, bj;
  bool diag;
  if (blockIdx.x < 32) {
    bi = blockIdx.x; bj = bi >> 1; diag = true;
  } else {
    int idx = blockIdx.x - 32;                // 0..239
    int j = 0;                                 // off(j) = j*(31-j)
    while (j < 14 && idx >= (j + 1) * (30 - j)) ++j;
    bj = j;
    bi = 2 * j + 2 + (idx - j * (31 - j));
    diag = false;
  }

  __shared__ __align__(16) char smem[49152];   // 48KB staging; Cred aliases after
  unsigned short* Xs = (unsigned short*)smem;             // [half][buf][64*32]
  unsigned short* Ys = (unsigned short*)(smem + 16384);   // [half][buf][128*32]
  float* Cred = (float*)smem;                             // [64*132] post-loop

  const int w = tid >> 6, lane = tid & 63;
  const int half = w >> 2, wq = w & 3;      // k-half, role within half
  const int row0 = bi * 64, col0 = bj * 128;
  const int m0 = (wq & 1) * 32, n0 = (wq >> 1) * 64;
  f32x4 acc[2][4];
#pragma unroll
  for (int a = 0; a < 2; ++a)
#pragma unroll
    for (int b = 0; b < 4; ++b) acc[a][b] = (f32x4){0.f, 0.f, 0.f, 0.f};
  const int mrow = lane & 15, kseg = (lane >> 4) * 8;
  const int srowX = wq * 16 + (lane >> 2);
  const int srowY = wq * 32 + (lane >> 2);
  const int scol = (lane & 3) * 8;
  const int kbase = half * 1024;

  stage_tiles2(Gh, Xs + (half * 2 + 0) * 2048, Ys + (half * 2 + 0) * 4096,
               row0, col0, kbase, srowX, srowY, scol, wq);
  for (int t = 0; t < 32; ++t) {
    const int cur = t & 1;
    __syncthreads();
    if (t < 31)
      stage_tiles2(Gh, Xs + (half * 2 + (cur ^ 1)) * 2048,
                   Ys + (half * 2 + (cur ^ 1)) * 4096,
                   row0, col0, kbase + (t + 1) * 32, srowX, srowY, scol, wq);
    const unsigned short* Xb = Xs + (half * 2 + cur) * 2048;
    const unsigned short* Yb = Ys + (half * 2 + cur) * 4096;
    half8 af[2], bf[4];
#pragma unroll
    for (int q = 0; q < 2; ++q)
      af[q] = *(const half8*)(Xb + (m0 + q * 16 + mrow) * 32 + kseg);
#pragma unroll
    for (int q = 0; q < 4; ++q)
      bf[q] = *(const half8*)(Yb + (n0 + q * 16 + mrow) * 32 + kseg);
#pragma unroll
    for (int mt = 0; mt < 2; ++mt)
#pragma unroll
      for (int nt = 0; nt < 4; ++nt)
        acc[mt][nt] = __builtin_amdgcn_mfma_f32_16x16x32_f16(af[mt], bf[nt], acc[mt][nt], 0, 0, 0);
  }
  // combine halves; epilogue applies /N + I; fp32 direct + fp32 mirror.
  // C/D layout: col=lane&15, row=(lane>>4)*4+reg  [m89-verified]
  const int crow = (lane >> 4) * 4, ccol = lane & 15;
  __syncthreads();
  if (half == 1) {
#pragma unroll
    for (int mt = 0; mt < 2; ++mt)
#pragma unroll
      for (int nt = 0; nt < 4; ++nt)
#pragma unroll
        for (int r = 0; r < 4; ++r)
          Cred[(m0 + mt * 16 + crow + r) * 132 + n0 + nt * 16 + ccol] = acc[mt][nt][r];
  }
  __syncthreads();
  if (half == 0) {
    const float invn = 1.0f / 2048.0f;
#pragma unroll
    for (int mt = 0; mt < 2; ++mt)
#pragma unroll
      for (int nt = 0; nt < 4; ++nt) {
        const int gi0 = row0 + m0 + mt * 16 + crow;
        const int gj = col0 + n0 + nt * 16 + ccol;
        size_t base = (size_t)gi0 * 2048 + gj;
#pragma unroll
        for (int r = 0; r < 4; ++r) {
          const int li = (m0 + mt * 16 + crow + r) * 132 + n0 + nt * 16 + ccol;
          float val = (acc[mt][nt][r] + Cred[li]) * invn +
                      ((gi0 + r == gj) ? 1.0f : 0.0f);
          M[base + (size_t)r * 2048] = val;
          if (!diag) Cred[li] = val;        // park final value for mirror pass
        }
      }
  }
  if (!diag) {
    __syncthreads();                         // Cred holds the final fp32 tile
    const int orow = tid >> 2;               // 0..127 (original tile col)
    const int cseg = (tid & 3) * 16;         // 0..48  (original tile row base)
    float mv[16];
#pragma unroll
    for (int k = 0; k < 16; ++k)
      mv[k] = Cred[(cseg + k) * 132 + orow];
    float4* dst = (float4*)(M + (size_t)(col0 + orow) * 2048 + row0 + cseg);
    dst[0] = (float4){mv[0], mv[1], mv[2], mv[3]};
    dst[1] = (float4){mv[4], mv[5], mv[6], mv[7]};
    dst[2] = (float4){mv[8], mv[9], mv[10], mv[11]};
    dst[3] = (float4){mv[12], mv[13], mv[14], mv[15]};
  }
}

// ---- deterministic block-wide sum over 8 waves: bitwise-identical per block ----
__device__ __forceinline__ float block_sum8(float v, float* red) {
#pragma unroll
  for (int off = 32; off; off >>= 1) v += __shfl_down(v, off);
  if ((threadIdx.x & 63) == 0) red[threadIdx.x >> 6] = v;
  __syncthreads();
  float r = ((red[0] + red[1]) + (red[2] + red[3])) +
            ((red[4] + red[5]) + (red[6] + red[7]));
  __syncthreads();
  return r;
}

// ---- 5. Lanczos: single-phase epoch protocol, 128 x 512 — FROZEN core (R20) ----
// R20: ~4.2 us/iter exchange is the store->remote-observability floor.
// RULE 1 (R1/R6): cross-block data via agent-scope atomics only.
// RULE 2 (R1/R6/R8): beta^2 = ||z - alpha v||^2 DIRECT form only.
// RULE 3 (R16): no fixed-address staging reuse with plain cached loads.
// RULE 4 (R17): exactly ONE publish->consume phase per iteration.
// RULE 5 (R19/R20): exchange cost is per-phase visibility latency.
// RULE 6 (R14/R15/R31): NO dependent-load chains anywhere (LDS included).
// Sparse apply reads pre-expanded packed lists (coalesced) + LDS atomics.
// Single producer per Z row -> block-redundant scalar invariant intact.
__global__ __launch_bounds__(512) void lanczos_kernel(const float* __restrict__ M,
                                                      const unsigned* __restrict__ listCnt,
                                                      const int* __restrict__ colList,
                                                      const float* __restrict__ valList,
                                                      unsigned long long* __restrict__ Z0,
                                                      unsigned long long* __restrict__ Z1,
                                                      float* __restrict__ out) {
  const int tid = threadIdx.x, b = blockIdx.x;
  const int wave = tid >> 6, lane = tid & 63;
  __shared__ __align__(16) float Mlds[16 * 2048];  // 128 KB: this block's 16 rows
  __shared__ __align__(16) float VA[2048];
  __shared__ __align__(16) float VB[2048];
  __shared__ float red[8];
  __shared__ float al[LK + 2], b2[LK + 2];
  __shared__ float bnds[2], res[2];

  const float* Mblk = M + (size_t)b * 16 * 2048;
#pragma unroll
  for (int q = 0; q < 16; ++q)
    __builtin_amdgcn_global_load_lds(AS1C(Mblk + wave * 4096 + q * 256 + lane * 4),
                                     AS3(Mlds + wave * 4096 + q * 256), 16, 0, 0);

  // block-redundant init: v1 = hash / ||hash||  (identical in every block), v0 = 0
  float pv[4];
  float part = 0.f;
#pragma unroll
  for (int t = 0; t < 4; ++t) {
    int i = t * 512 + tid;
    unsigned u = (unsigned)i * 2654435761u;
    u ^= u >> 16; u *= 2246822519u; u ^= u >> 13;
    float rv = (float)(u >> 8) * (2.f / 16777216.f) - 1.f;
    pv[t] = rv;
    part += rv * rv;
  }
  float nrm = block_sum8(part, red);       // barriers inside drain Mlds staging
  float innm = rsqrtf(nrm);
#pragma unroll
  for (int t = 0; t < 4; ++t) {
    int i = t * 512 + tid;
    VA[i] = pv[t] * innm;
    VB[i] = 0.f;
  }
  __syncthreads();                         // Mlds fully staged; VA/VB ready

  // ---- apply packed sparse lists to this block's rows (coalesced) ----
  for (int rr = 0; rr < 2; ++rr) {
    const int r = b * 16 + wave * 2 + rr;
    float* Mrow = Mlds + (wave * 2 + rr) * 2048;
    const unsigned n = min(listCnt[r], (unsigned)LCAP);
    const int* cl = colList + (size_t)r * LCAP;
    const float* vl = valList + (size_t)r * LCAP;
    for (unsigned i = lane; i < n; i += 64)
      atomicAdd(&Mrow[cl[i]], vl[i]);
  }
  __syncthreads();                         // sparse apply complete

  float* Vcur = VA;
  float* Vprev = VB;
  float beta_prev = 0.f;

  for (int j = 1; j <= LK; ++j) {
    unsigned long long* Z = (j & 1) ? Z0 : Z1;
#pragma unroll
    for (int rr = 0; rr < 2; ++rr) {
      const int r = b * 16 + wave * 2 + rr;
      const float4* Mr = (const float4*)(Mlds + (wave * 2 + rr) * 2048);
      float s = 0.f;
#pragma unroll
      for (int t = 0; t < 8; ++t) {
        int idx = t * 64 + lane;
        float4 m4 = Mr[idx];
        float4 v4 = ((const float4*)Vcur)[idx];
        s += m4.x * v4.x + m4.y * v4.y + m4.z * v4.z + m4.w * v4.w;
      }
#pragma unroll
      for (int off = 32; off; off >>= 1) s += __shfl_down(s, off);
      if (lane == 0) {
        float zv = s - beta_prev * Vprev[r];
        unsigned long long pk = ((unsigned long long)(unsigned)j << 32) |
                                (unsigned long long)(unsigned)__float_as_uint(zv);
        __hip_atomic_store(&Z[r], pk, __ATOMIC_RELAXED, AGENT);
      }
    }

    // hoist own v-slice reads (LDS) ahead of the poll — free overlap
    float va[4];
#pragma unroll
    for (int t = 0; t < 4; ++t) va[t] = Vcur[t * 512 + tid];

    unsigned long long w4[4];
    int rounds = 0;
    for (;;) {
      bool ok = true;
#pragma unroll
      for (int t = 0; t < 4; ++t) {
        w4[t] = __hip_atomic_load(&Z[t * 512 + tid], __ATOMIC_RELAXED, AGENT);
        ok &= ((unsigned)(w4[t] >> 32) == (unsigned)j);
      }
      if (ok) break;
      if (rounds == 1)      __builtin_amdgcn_s_sleep(1);   //  64 clk
      else if (rounds == 2) __builtin_amdgcn_s_sleep(2);   // 128 clk
      else if (rounds >= 3) __builtin_amdgcn_s_sleep(8);   // 512 clk
      ++rounds;
    }
    float za[4];
    float pa = 0.f;
#pragma unroll
    for (int t = 0; t < 4; ++t) {
      za[t] = __uint_as_float((unsigned)w4[t]);
      pa += za[t] * va[t];
    }
    float alpha = block_sum8(pa, red);
    float pb = 0.f;
#pragma unroll
    for (int t = 0; t < 4; ++t) {
      float rsd = za[t] - alpha * va[t];
      pb += rsd * rsd;
    }
    float beta2 = block_sum8(pb, red);
    float beta = sqrtf(fmaxf(beta2, 1e-30f));
    float invb = 1.f / beta;
    if (tid == 0) { al[j] = alpha; b2[j] = beta2; }
#pragma unroll
    for (int t = 0; t < 4; ++t) {
      int i = t * 512 + tid;
      Vprev[i] = (za[t] - alpha * va[t]) * invb;
    }
    float* tmp = Vprev; Vprev = Vcur; Vcur = tmp;
    beta_prev = beta;
    __syncthreads();
  }

  // ---- extreme eigenvalues of T via Sturm bisection (block 0) ----
  if (b == 0) {
    if (tid == 0) {                                  // Gershgorin bounds on T
      float lo = 1e30f, hi = -1e30f;
      for (int i = 1; i <= LK; ++i) {
        float bl = (i > 1) ? sqrtf(b2[i - 1]) : 0.f;
        float br = (i < LK) ? sqrtf(b2[i]) : 0.f;
        lo = fminf(lo, al[i] - bl - br);
        hi = fmaxf(hi, al[i] + bl + br);
      }
      bnds[0] = lo; bnds[1] = hi;
    }
    __syncthreads();
    if (wave < 2) {                 // wave 0 -> lambda_min, wave 1 -> lambda_max
      const int tcount = (wave == 0) ? 1 : LK;
      float lo = bnds[0], hi = bnds[1];
      for (int round = 0; round < 4; ++round) {
        float x = lo + (hi - lo) * (float)(lane + 1) * (1.f / 65.f);
        int cnt = 0;                                 // #eigs of T below x
        float d = al[1] - x;
        if (fabsf(d) < 1e-25f) d = -1e-25f;
        if (d < 0.f) cnt++;
        for (int i = 2; i <= LK; ++i) {
          d = (al[i] - x) - b2[i - 1] / d;
          if (fabsf(d) < 1e-25f) d = -1e-25f;
          if (d < 0.f) cnt++;
        }
        bool ab = (cnt >= tcount);                   // x is above the target eig
        float cand_hi = ab ? x : hi;
        float cand_lo = ab ? lo : x;
#pragma unroll
        for (int off = 32; off; off >>= 1) {
          cand_hi = fminf(cand_hi, __shfl_down(cand_hi, off));
          cand_lo = fmaxf(cand_lo, __shfl_down(cand_lo, off));
        }
        cand_hi = __shfl(cand_hi, 0);
        cand_lo = __shfl(cand_lo, 0);
        hi = cand_hi;
        lo = fminf(cand_lo, hi);
      }
      if (lane == 0) res[wave] = 0.5f * (lo + hi);
    }
    __syncthreads();
    if (tid == 0) {
      float lmin = fmaxf(res[0], 1e-12f);
      float lmax = fmaxf(res[1], 1e-12f);
      out[0] = logf(lmax) - logf(lmin);
    }
  }
}

extern "C" void kernel_launch(void* const* d_in, const int* in_sizes, int n_in,
                              void* d_out, int out_size, void* d_ws, size_t ws_size,
                              hipStream_t stream) {
  const float* pred = (const float*)d_in[0];
  const float* scal = (const float*)d_in[1];
  const float* W    = (const float*)d_in[2];
  const int*   rows = (const int*)d_in[3];
  const int*   cols = (const int*)d_in[4];
  float* out = (float*)d_out;

  // workspace layout (peak ~46.2 MB):
  //  [0,8MB)   : Hf fp16
  //  [8,16MB)  : Gh fp16 (G = L*Wh)
  //  [16,32MB) : M fp32
  //  [32,38MB) : colList int  (2048 x 768)
  //  [38,44MB) : valList f32  (2048 x 768)
  //  [44MB,..) : cntR 8KB | cntC 8KB | binRc 512KB | binRv 512KB |
  //              binCr 512KB | binCv 512KB | listCnt 8KB | Z0 16KB | Z1 16KB
  char* ws = (char*)d_ws;
  const size_t MB = 1024 * 1024;
  unsigned short* Hf = (unsigned short*)(ws);
  unsigned short* Gh = (unsigned short*)(ws + 8 * MB);
  float* M = (float*)(ws + 16 * MB);
  int*   colList = (int*)(ws + 32 * MB);
  float* valList = (float*)(ws + 38 * MB);
  char* ctrl = ws + 44 * MB;
  unsigned* cntR = (unsigned*)(ctrl);
  unsigned* cntC = (unsigned*)(ctrl + 8192);
  int*      binRc = (int*)(ctrl + 16384);
  float*    binRv = (float*)(ctrl + 16384 + 524288);
  int*      binCr = (int*)(ctrl + 16384 + 2 * 524288);
  float*    binCv = (float*)(ctrl + 16384 + 3 * 524288);
  unsigned* listCnt = (unsigned*)(ctrl + 16384 + 4 * 524288);
  unsigned long long* Z0 = (unsigned long long*)(ctrl + 16384 + 4 * 524288 + 8192);
  unsigned long long* Z1 = (unsigned long long*)(ctrl + 16384 + 4 * 524288 + 8192 + 16384);

  convert_kernel<<<4096, 256, 0, stream>>>(W, Hf, cntR, cntC);
  fill_kernel<<<NNZ / 256, 256, 0, stream>>>(pred, scal, rows, cols,
                                             cntR, binRc, binRv, cntC, binCr, binCv);
  expand_kernel<<<2048, 256, 0, stream>>>(cntR, binRc, binRv, cntC, binCr, binCv,
                                          colList, valList, listCnt);
  gatherG_kernel<<<2048, 256, 0, stream>>>(cntR, binRc, binRv, Hf, Gh);  // G = L*Wh
  gemmM_kernel<<<272, 512, 0, stream>>>(Gh, M);                          // M = GG^T/N + I
  lanczos_kernel<<<NBL, 512, 0, stream>>>(M, listCnt, colList, valList,
                                          Z0, Z1, out);
}